// Round 1
// baseline (559.110 us; speedup 1.0000x reference)
//
#include <hip/hip_runtime.h>

// MCH remap via cell-indexed Bloom signatures + aux-window exact resolution.
//
// Round-4 change: cells 2^19 -> 2^20 (cell = v>>11, ~4 table keys/cell).
// Rationale: divergence is wave-granular. At fp ~3%/element, P(wave takes
// the resolve path) = 1-0.97^64 ~ 87% per element -> ~7 serialized
// ~1000-cycle dependent resolve chains per wave (the measured 293us vs
// 45us streaming floor; VALUBusy 36%, hbm 31% = latency-bound).
// At 4 keys/cell, fp = (1-e^-16/64)^4 ~ 0.24%/element; with true hits
// (0.195%) wave-resolve prob drops 87% -> ~24%/element, ~1.9 resolves/wave.
// Filter 8 MB + aux 4 MB: L2/L3 resident. Tiered fallback to the previous
// 2^19 (6 MB) config, then aux-only, if ws is small.
//
// Resolution invariants (any sorted table, any cell shift SH):
//   idx <  aux[k]   => table[idx] <  (k<<SH)    <= v  (counted, all < v)
//   idx >= aux[k+1] => table[idx] >= (k+1)<<SH  >  v  (never counted/eq)
// and if table[m] == v the clamped-to-z window includes index m.

typedef int vint4 __attribute__((ext_vector_type(4)));
typedef unsigned long long u64;

#define HK 2654435761u                      // Knuth multiplicative hash

__device__ __forceinline__ u64 sig_mask(unsigned v) {
    unsigned h = v * HK;                    // bits 8..31 used, disjoint 6-bit fields
    return (1ULL << (h >> 26)) | (1ULL << ((h >> 20) & 63)) |
           (1ULL << ((h >> 14) & 63)) | (1ULL << ((h >> 8) & 63));
}

// ---- build 1: aux[k] = lower_bound(table[:m], k<<SH), O(z) scatter ----
template <int BITS>
__global__ __launch_bounds__(256) void build_aux_scatter(
    const int* __restrict__ table, int m, int* __restrict__ aux) {
    const int SH = 31 - BITS;
    const unsigned NB = 1u << BITS;
    int j = blockIdx.x * blockDim.x + threadIdx.x;
    if (j >= m) return;
    unsigned lo_k = (j == 0) ? 0u : ((((unsigned)table[j - 1]) >> SH) + 1u);
    unsigned hi_k = ((unsigned)table[j]) >> SH;
    for (unsigned k = lo_k; k <= hi_k; ++k) aux[k] = j;
    if (j == m - 1) {
        for (unsigned k = hi_k + 1; k <= NB; ++k) aux[k] = m;
    }
}

// ---- build 2: per-cell signature, sequential reads, plain store ----
template <int BITS>
__global__ __launch_bounds__(256) void build_sigs(
    const int* __restrict__ table, const int* __restrict__ aux, int z,
    u64* __restrict__ filter) {
    const int SH = 31 - BITS;
    const unsigned NB = 1u << BITS;
    unsigned k = blockIdx.x * blockDim.x + threadIdx.x;
    if (k >= NB) return;
    int p = aux[k];
    u64 sig = 0;
    while (p < z && ((((unsigned)table[p]) >> SH) == k)) {
        sig |= sig_mask((unsigned)table[p]);
        ++p;
    }
    filter[k] = sig;
}

// ---- exact resolution for filter-positive lanes ----
template <int BITS>
__device__ __forceinline__ int resolve_window(
    int v, const int* __restrict__ table, const int* __restrict__ mapping,
    const int* __restrict__ aux, int z, int zch) {
    const int SH = 31 - BITS;
    unsigned k = ((unsigned)v) >> SH;
    int lo = aux[k];
    int hi = aux[k + 1];
    int s = lo & ~3;
    int e = (hi + 3) & ~3;
    if (e > z) e = z;
    int cnt = 0;
    bool eq = false;
    for (int p = s; p < e; p += 4) {
        int4 t = *(const int4*)(table + p);
        cnt += (t.x < v) + (t.y < v) + (t.z < v) + (t.w < v);
        eq = eq | (t.x == v) | (t.y == v) | (t.z == v) | (t.w == v);
    }
    if (eq) return mapping[s + cnt];
    return zch;
}

// ---- main: 8 values/thread (two coalesced int4 segments) ----
template <int BITS>
__global__ __launch_bounds__(256) void mch_remap_bloom_kernel(
    const vint4* __restrict__ values4,
    const int* __restrict__ table,
    const int* __restrict__ mapping,
    const int* __restrict__ zch_p,
    const int* __restrict__ aux,
    const u64* __restrict__ filter,
    vint4* __restrict__ out4,
    int half4, int z) {
    const int SH = 31 - BITS;

    int zch = *zch_p;
    int i = blockIdx.x * blockDim.x + threadIdx.x;
    if (i >= half4) return;

    vint4 va = __builtin_nontemporal_load(values4 + i);
    vint4 vb = __builtin_nontemporal_load(values4 + i + half4);
    int v[8] = {va.x, va.y, va.z, va.w, vb.x, vb.y, vb.z, vb.w};

    u64 w[8];
#pragma unroll
    for (int e = 0; e < 8; ++e) w[e] = filter[((unsigned)v[e]) >> SH];

    int res[8];
#pragma unroll
    for (int e = 0; e < 8; ++e) {
        u64 mask = sig_mask((unsigned)v[e]);
        bool maybe = (w[e] & mask) == mask;      // ~0.43% of lanes (fp + hits)
        int r = zch;
        if (__builtin_expect(maybe, 0))
            r = resolve_window<BITS>(v[e], table, mapping, aux, z, zch);
        res[e] = r;
    }
    vint4 oa, ob;
    oa.x = res[0]; oa.y = res[1]; oa.z = res[2]; oa.w = res[3];
    ob.x = res[4]; ob.y = res[5]; ob.z = res[6]; ob.w = res[7];
    __builtin_nontemporal_store(oa, out4 + i);
    __builtin_nontemporal_store(ob, out4 + i + half4);
}

// scalar tail (n % 8 != 0)
template <int BITS>
__global__ __launch_bounds__(64) void mch_remap_tail_kernel(
    const int* __restrict__ values, const int* __restrict__ table,
    const int* __restrict__ mapping, const int* __restrict__ zch_p,
    const int* __restrict__ aux, const u64* __restrict__ filter,
    int* __restrict__ out, int start, int n, int z) {
    const int SH = 31 - BITS;
    int i = start + blockIdx.x * blockDim.x + threadIdx.x;
    if (i >= n) return;
    int v = values[i];
    u64 w = filter[((unsigned)v) >> SH];
    u64 mask = sig_mask((unsigned)v);
    int zch = *zch_p;
    out[i] = ((w & mask) == mask)
                 ? resolve_window<BITS>(v, table, mapping, aux, z, zch) : zch;
}

// ---- fallback: aux-only windowed count, ~2 MB ws ----
__global__ __launch_bounds__(256) void mch_remap_aux_kernel(
    const int* __restrict__ values, const int* __restrict__ table,
    const int* __restrict__ mapping, const int* __restrict__ zch_p,
    const int* __restrict__ aux, int* __restrict__ out, int n, int z) {
    int zch = *zch_p;
    int i = blockIdx.x * blockDim.x + threadIdx.x;
    if (i >= n) return;
    int v = __builtin_nontemporal_load(values + i);
    out[i] = resolve_window<19>(v, table, mapping, aux, z, zch);
}

template <int BITS>
static void run_bloom(const int* values, const int* table, const int* mapping,
                      const int* zch_p, int* out, int n, int z, int m,
                      void* d_ws, hipStream_t stream) {
    const unsigned NB = 1u << BITS;
    u64* filter = (u64*)d_ws;
    int* aux = (int*)((char*)d_ws + (size_t)NB * 8);
    const int block = 256;

    build_aux_scatter<BITS><<<(m + block - 1) / block, block, 0, stream>>>(
        table, m, aux);
    build_sigs<BITS><<<((int)NB + block - 1) / block, block, 0, stream>>>(
        table, aux, z, filter);

    int half4 = n >> 3;                  // int4 units per segment
    if (half4 > 0) {
        mch_remap_bloom_kernel<BITS><<<(half4 + block - 1) / block, block, 0, stream>>>(
            (const vint4*)values, table, mapping, zch_p, aux, filter,
            (vint4*)out, half4, z);
    }
    int done = (half4 << 3);
    if (done < n) {
        mch_remap_tail_kernel<BITS><<<((n - done) + 63) / 64, 64, 0, stream>>>(
            values, table, mapping, zch_p, aux, filter, out, done, n, z);
    }
}

extern "C" void kernel_launch(void* const* d_in, const int* in_sizes, int n_in,
                              void* d_out, int out_size, void* d_ws, size_t ws_size,
                              hipStream_t stream) {
    const int* values  = (const int*)d_in[0];
    const int* table   = (const int*)d_in[1];
    const int* mapping = (const int*)d_in[2];
    const int* zch_p   = (const int*)d_in[3];
    int* out = (int*)d_out;

    int n = in_sizes[0];          // 33_554_432
    int z = in_sizes[1];          // 4_194_304
    int m = z - 1;

    const size_t need20 = (size_t)(1u << 20) * 8 + ((size_t)(1u << 20) + 1) * 4;
    const size_t need19 = (size_t)(1u << 19) * 8 + ((size_t)(1u << 19) + 1) * 4;
    const size_t aux19  = ((size_t)(1u << 19) + 1) * 4;
    const int block = 256;

    if (ws_size >= need20) {
        run_bloom<20>(values, table, mapping, zch_p, out, n, z, m, d_ws, stream);
    } else if (ws_size >= need19) {
        run_bloom<19>(values, table, mapping, zch_p, out, n, z, m, d_ws, stream);
    } else if (ws_size >= aux19) {
        int* aux = (int*)d_ws;
        build_aux_scatter<19><<<(m + block - 1) / block, block, 0, stream>>>(
            table, m, aux);
        mch_remap_aux_kernel<<<(n + block - 1) / block, block, 0, stream>>>(
            values, table, mapping, zch_p, aux, out, n, z);
    }
}

// Round 2
// 513.260 us; speedup vs baseline: 1.0893x; 1.0893x over previous
//
#include <hip/hip_runtime.h>

// MCH remap via cell-indexed Bloom signatures + aux-window exact resolution.
//
// Round-5: revert to 2^19 cells (4 MB filter, per-XCD-L2-resident; the 2^20
// 8 MB variant doubled FETCH_SIZE to 1.2 GB and went fabric-BW-bound).
// New lever: positive-slot COMPACTION. At fp~2.7%, the old code's 8
// unrolled per-slot resolve branches each had P(wave enters)~0.83 ->
// ~6.7 serialized ~1000-cycle chains per wave with ~1.7/64 lanes active.
// Now each thread builds an 8-bit positive mask and loops while(pm):
// every lane resolves ITS OWN positive slot concurrently; wave iterations
// = max-lane popcount ~= 2. Dynamic v[e]/res[e] indexing would spill to
// scratch (runtime-indexed reg arrays), so slot extract = cndmask tree,
// result scatter = 8 cndmasks. Table/mapping resolve loads are
// nontemporal to protect filter residency in L2.
//
// Resolution invariants (any sorted table, any cell shift SH):
//   idx <  aux[k]   => table[idx] <  (k<<SH)    <= v  (counted, all < v)
//   idx >= aux[k+1] => table[idx] >= (k+1)<<SH  >  v  (never counted/eq)
// and if table[m] == v the clamped-to-z window includes index m.

typedef int vint4 __attribute__((ext_vector_type(4)));
typedef unsigned long long u64;

#define HK 2654435761u                      // Knuth multiplicative hash

__device__ __forceinline__ u64 sig_mask(unsigned v) {
    unsigned h = v * HK;                    // bits 8..31 used, disjoint 6-bit fields
    return (1ULL << (h >> 26)) | (1ULL << ((h >> 20) & 63)) |
           (1ULL << ((h >> 14) & 63)) | (1ULL << ((h >> 8) & 63));
}

// ---- build 1: aux[k] = lower_bound(table[:m], k<<SH), O(z) scatter ----
template <int BITS>
__global__ __launch_bounds__(256) void build_aux_scatter(
    const int* __restrict__ table, int m, int* __restrict__ aux) {
    const int SH = 31 - BITS;
    const unsigned NB = 1u << BITS;
    int j = blockIdx.x * blockDim.x + threadIdx.x;
    if (j >= m) return;
    unsigned lo_k = (j == 0) ? 0u : ((((unsigned)table[j - 1]) >> SH) + 1u);
    unsigned hi_k = ((unsigned)table[j]) >> SH;
    for (unsigned k = lo_k; k <= hi_k; ++k) aux[k] = j;
    if (j == m - 1) {
        for (unsigned k = hi_k + 1; k <= NB; ++k) aux[k] = m;
    }
}

// ---- build 2: per-cell signature, sequential reads, plain store ----
template <int BITS>
__global__ __launch_bounds__(256) void build_sigs(
    const int* __restrict__ table, const int* __restrict__ aux, int z,
    u64* __restrict__ filter) {
    const int SH = 31 - BITS;
    const unsigned NB = 1u << BITS;
    unsigned k = blockIdx.x * blockDim.x + threadIdx.x;
    if (k >= NB) return;
    int p = aux[k];
    u64 sig = 0;
    while (p < z && ((((unsigned)table[p]) >> SH) == k)) {
        sig |= sig_mask((unsigned)table[p]);
        ++p;
    }
    filter[k] = sig;
}

// ---- exact resolution for filter-positive lanes ----
template <int BITS>
__device__ __forceinline__ int resolve_window(
    int v, const int* __restrict__ table, const int* __restrict__ mapping,
    const int* __restrict__ aux, int z, int zch) {
    const int SH = 31 - BITS;
    unsigned k = ((unsigned)v) >> SH;
    int lo = aux[k];
    int hi = aux[k + 1];
    int s = lo & ~3;
    int e = (hi + 3) & ~3;
    if (e > z) e = z;
    int cnt = 0;
    bool eq = false;
    for (int p = s; p < e; p += 4) {
        vint4 t = __builtin_nontemporal_load((const vint4*)(table + p));
        cnt += (t.x < v) + (t.y < v) + (t.z < v) + (t.w < v);
        eq = eq | (t.x == v) | (t.y == v) | (t.z == v) | (t.w == v);
    }
    if (eq) return __builtin_nontemporal_load(mapping + s + cnt);
    return zch;
}

// ---- main: 8 values/thread, compacted positive-slot resolve loop ----
template <int BITS>
__global__ __launch_bounds__(256) void mch_remap_bloom_kernel(
    const vint4* __restrict__ values4,
    const int* __restrict__ table,
    const int* __restrict__ mapping,
    const int* __restrict__ zch_p,
    const int* __restrict__ aux,
    const u64* __restrict__ filter,
    vint4* __restrict__ out4,
    int half4, int z) {
    const int SH = 31 - BITS;

    int zch = *zch_p;
    int i = blockIdx.x * blockDim.x + threadIdx.x;
    if (i >= half4) return;

    vint4 va = __builtin_nontemporal_load(values4 + i);
    vint4 vb = __builtin_nontemporal_load(values4 + i + half4);
    int v[8] = {va.x, va.y, va.z, va.w, vb.x, vb.y, vb.z, vb.w};

    u64 w[8];
#pragma unroll
    for (int e = 0; e < 8; ++e) w[e] = filter[((unsigned)v[e]) >> SH];

    unsigned pm = 0;
#pragma unroll
    for (int e = 0; e < 8; ++e) {
        u64 mask = sig_mask((unsigned)v[e]);
        if ((w[e] & mask) == mask) pm |= (1u << e);   // ~2.9% of slots
    }

    int r0 = zch, r1 = zch, r2 = zch, r3 = zch;
    int r4 = zch, r5 = zch, r6 = zch, r7 = zch;

    // Wave iterates max-over-lanes popcount(pm) times (~2), each lane
    // resolving its own positive slot — vs 8 serialized per-slot entries.
    while (pm) {
        int e = __builtin_ctz(pm);
        pm &= pm - 1;
        // 8-way register select (static indices only -> stays in VGPRs)
        int x01 = (e & 1) ? v[1] : v[0];
        int x23 = (e & 1) ? v[3] : v[2];
        int x45 = (e & 1) ? v[5] : v[4];
        int x67 = (e & 1) ? v[7] : v[6];
        int x03 = (e & 2) ? x23 : x01;
        int x47 = (e & 2) ? x67 : x45;
        int ve  = (e & 4) ? x47 : x03;

        int r = resolve_window<BITS>(ve, table, mapping, aux, z, zch);

        r0 = (e == 0) ? r : r0;
        r1 = (e == 1) ? r : r1;
        r2 = (e == 2) ? r : r2;
        r3 = (e == 3) ? r : r3;
        r4 = (e == 4) ? r : r4;
        r5 = (e == 5) ? r : r5;
        r6 = (e == 6) ? r : r6;
        r7 = (e == 7) ? r : r7;
    }

    vint4 oa, ob;
    oa.x = r0; oa.y = r1; oa.z = r2; oa.w = r3;
    ob.x = r4; ob.y = r5; ob.z = r6; ob.w = r7;
    __builtin_nontemporal_store(oa, out4 + i);
    __builtin_nontemporal_store(ob, out4 + i + half4);
}

// scalar tail (n % 8 != 0)
template <int BITS>
__global__ __launch_bounds__(64) void mch_remap_tail_kernel(
    const int* __restrict__ values, const int* __restrict__ table,
    const int* __restrict__ mapping, const int* __restrict__ zch_p,
    const int* __restrict__ aux, const u64* __restrict__ filter,
    int* __restrict__ out, int start, int n, int z) {
    const int SH = 31 - BITS;
    int i = start + blockIdx.x * blockDim.x + threadIdx.x;
    if (i >= n) return;
    int v = values[i];
    u64 w = filter[((unsigned)v) >> SH];
    u64 mask = sig_mask((unsigned)v);
    int zch = *zch_p;
    out[i] = ((w & mask) == mask)
                 ? resolve_window<BITS>(v, table, mapping, aux, z, zch) : zch;
}

// ---- fallback: aux-only windowed count, ~2 MB ws ----
__global__ __launch_bounds__(256) void mch_remap_aux_kernel(
    const int* __restrict__ values, const int* __restrict__ table,
    const int* __restrict__ mapping, const int* __restrict__ zch_p,
    const int* __restrict__ aux, int* __restrict__ out, int n, int z) {
    int zch = *zch_p;
    int i = blockIdx.x * blockDim.x + threadIdx.x;
    if (i >= n) return;
    int v = __builtin_nontemporal_load(values + i);
    out[i] = resolve_window<19>(v, table, mapping, aux, z, zch);
}

template <int BITS>
static void run_bloom(const int* values, const int* table, const int* mapping,
                      const int* zch_p, int* out, int n, int z, int m,
                      void* d_ws, hipStream_t stream) {
    const unsigned NB = 1u << BITS;
    u64* filter = (u64*)d_ws;
    int* aux = (int*)((char*)d_ws + (size_t)NB * 8);
    const int block = 256;

    build_aux_scatter<BITS><<<(m + block - 1) / block, block, 0, stream>>>(
        table, m, aux);
    build_sigs<BITS><<<((int)NB + block - 1) / block, block, 0, stream>>>(
        table, aux, z, filter);

    int half4 = n >> 3;                  // int4 units per segment
    if (half4 > 0) {
        mch_remap_bloom_kernel<BITS><<<(half4 + block - 1) / block, block, 0, stream>>>(
            (const vint4*)values, table, mapping, zch_p, aux, filter,
            (vint4*)out, half4, z);
    }
    int done = (half4 << 3);
    if (done < n) {
        mch_remap_tail_kernel<BITS><<<((n - done) + 63) / 64, 64, 0, stream>>>(
            values, table, mapping, zch_p, aux, filter, out, done, n, z);
    }
}

extern "C" void kernel_launch(void* const* d_in, const int* in_sizes, int n_in,
                              void* d_out, int out_size, void* d_ws, size_t ws_size,
                              hipStream_t stream) {
    const int* values  = (const int*)d_in[0];
    const int* table   = (const int*)d_in[1];
    const int* mapping = (const int*)d_in[2];
    const int* zch_p   = (const int*)d_in[3];
    int* out = (int*)d_out;

    int n = in_sizes[0];          // 33_554_432
    int z = in_sizes[1];          // 4_194_304
    int m = z - 1;

    const size_t need19 = (size_t)(1u << 19) * 8 + ((size_t)(1u << 19) + 1) * 4;
    const size_t aux19  = ((size_t)(1u << 19) + 1) * 4;
    const int block = 256;

    if (ws_size >= need19) {
        run_bloom<19>(values, table, mapping, zch_p, out, n, z, m, d_ws, stream);
    } else if (ws_size >= aux19) {
        int* aux = (int*)d_ws;
        build_aux_scatter<19><<<(m + block - 1) / block, block, 0, stream>>>(
            table, m, aux);
        mch_remap_aux_kernel<<<(n + block - 1) / block, block, 0, stream>>>(
            values, table, mapping, zch_p, aux, out, n, z);
    }
}

// Round 3
// 471.208 us; speedup vs baseline: 1.1865x; 1.0892x over previous
//
#include <hip/hip_runtime.h>

// MCH remap via cell-indexed Bloom signatures + aux-window exact resolution.
//
// Round-6: MLP scaling. Round-2 proved resolve is ~free (VALUBusy 36->14%
// with zero time change) -> the limiter is the 33.5M random 8B filter
// gathers, bounded by Little's law: 8 in-flight gathers/thread x ~21
// waves/CU ~= 43 outstanding/SIMD at ~550cy loaded L2/L3 latency ~= the
// measured 300us. Lever: 16 values/thread (4 coalesced int4 segments) ->
// ~2x outstanding requests. Filter stays 2^19 cells x u64 = 4 MB
// (L2-resident; round-1 showed 8 MB doubles fabric traffic). Table/mapping
// resolve loads back to CACHED (round-2's nt raised FETCH 583->641 MB).
// __launch_bounds__(256,5) caps VGPR ~102 to prevent spill/occupancy cliff.
//
// Resolution invariants (any sorted table, any cell shift SH):
//   idx <  aux[k]   => table[idx] <  (k<<SH)    <= v  (counted, all < v)
//   idx >= aux[k+1] => table[idx] >= (k+1)<<SH  >  v  (never counted/eq)
// and if table[m] == v the clamped-to-z window includes index m.

typedef int vint4 __attribute__((ext_vector_type(4)));
typedef unsigned long long u64;

#define HK 2654435761u                      // Knuth multiplicative hash

__device__ __forceinline__ u64 sig_mask(unsigned v) {
    unsigned h = v * HK;                    // bits 8..31 used, disjoint 6-bit fields
    return (1ULL << (h >> 26)) | (1ULL << ((h >> 20) & 63)) |
           (1ULL << ((h >> 14) & 63)) | (1ULL << ((h >> 8) & 63));
}

// ---- build 1: aux[k] = lower_bound(table[:m], k<<SH), O(z) scatter ----
template <int BITS>
__global__ __launch_bounds__(256) void build_aux_scatter(
    const int* __restrict__ table, int m, int* __restrict__ aux) {
    const int SH = 31 - BITS;
    const unsigned NB = 1u << BITS;
    int j = blockIdx.x * blockDim.x + threadIdx.x;
    if (j >= m) return;
    unsigned lo_k = (j == 0) ? 0u : ((((unsigned)table[j - 1]) >> SH) + 1u);
    unsigned hi_k = ((unsigned)table[j]) >> SH;
    for (unsigned k = lo_k; k <= hi_k; ++k) aux[k] = j;
    if (j == m - 1) {
        for (unsigned k = hi_k + 1; k <= NB; ++k) aux[k] = m;
    }
}

// ---- build 2: per-cell signature, sequential reads, plain store ----
template <int BITS>
__global__ __launch_bounds__(256) void build_sigs(
    const int* __restrict__ table, const int* __restrict__ aux, int z,
    u64* __restrict__ filter) {
    const int SH = 31 - BITS;
    const unsigned NB = 1u << BITS;
    unsigned k = blockIdx.x * blockDim.x + threadIdx.x;
    if (k >= NB) return;
    int p = aux[k];
    u64 sig = 0;
    while (p < z && ((((unsigned)table[p]) >> SH) == k)) {
        sig |= sig_mask((unsigned)table[p]);
        ++p;
    }
    filter[k] = sig;
}

// ---- exact resolution for filter-positive lanes (cached loads) ----
template <int BITS>
__device__ __forceinline__ int resolve_window(
    int v, const int* __restrict__ table, const int* __restrict__ mapping,
    const int* __restrict__ aux, int z, int zch) {
    const int SH = 31 - BITS;
    unsigned k = ((unsigned)v) >> SH;
    int lo = aux[k];
    int hi = aux[k + 1];
    int s = lo & ~3;
    int e = (hi + 3) & ~3;
    if (e > z) e = z;
    int cnt = 0;
    bool eq = false;
    for (int p = s; p < e; p += 4) {
        int4 t = *(const int4*)(table + p);
        cnt += (t.x < v) + (t.y < v) + (t.z < v) + (t.w < v);
        eq = eq | (t.x == v) | (t.y == v) | (t.z == v) | (t.w == v);
    }
    if (eq) return mapping[s + cnt];
    return zch;
}

// ---- main: 16 values/thread (four coalesced int4 segments) ----
template <int BITS>
__global__ __launch_bounds__(256, 5) void mch_remap_bloom_kernel(
    const vint4* __restrict__ values4,
    const int* __restrict__ table,
    const int* __restrict__ mapping,
    const int* __restrict__ zch_p,
    const int* __restrict__ aux,
    const u64* __restrict__ filter,
    vint4* __restrict__ out4,
    int q4, int z) {                     // q4 = int4 units per segment
    const int SH = 31 - BITS;

    int zch = *zch_p;
    int i = blockIdx.x * blockDim.x + threadIdx.x;
    if (i >= q4) return;

    vint4 va = __builtin_nontemporal_load(values4 + i);
    vint4 vb = __builtin_nontemporal_load(values4 + i + q4);
    vint4 vc = __builtin_nontemporal_load(values4 + i + 2 * q4);
    vint4 vd = __builtin_nontemporal_load(values4 + i + 3 * q4);
    int v[16] = {va.x, va.y, va.z, va.w, vb.x, vb.y, vb.z, vb.w,
                 vc.x, vc.y, vc.z, vc.w, vd.x, vd.y, vd.z, vd.w};

    // 16 independent in-flight gathers per thread — the MLP lever.
    u64 w[16];
#pragma unroll
    for (int e = 0; e < 16; ++e) w[e] = filter[((unsigned)v[e]) >> SH];

    unsigned pm = 0;
#pragma unroll
    for (int e = 0; e < 16; ++e) {
        u64 mask = sig_mask((unsigned)v[e]);
        if ((w[e] & mask) == mask) pm |= (1u << e);   // ~2.6% of slots
    }

    int r[16];
#pragma unroll
    for (int e = 0; e < 16; ++e) r[e] = zch;

    // Wave iterates max-over-lanes popcount(pm) (~3) times; each lane
    // resolves its own positive slot concurrently.
    while (pm) {
        int e = __builtin_ctz(pm);
        pm &= pm - 1;
        // 16-way register select, static indices only (stays in VGPRs)
        int a0 = (e & 1) ? v[1]  : v[0];
        int a1 = (e & 1) ? v[3]  : v[2];
        int a2 = (e & 1) ? v[5]  : v[4];
        int a3 = (e & 1) ? v[7]  : v[6];
        int a4 = (e & 1) ? v[9]  : v[8];
        int a5 = (e & 1) ? v[11] : v[10];
        int a6 = (e & 1) ? v[13] : v[12];
        int a7 = (e & 1) ? v[15] : v[14];
        int b0 = (e & 2) ? a1 : a0;
        int b1 = (e & 2) ? a3 : a2;
        int b2 = (e & 2) ? a5 : a4;
        int b3 = (e & 2) ? a7 : a6;
        int c0 = (e & 4) ? b1 : b0;
        int c1 = (e & 4) ? b3 : b2;
        int ve = (e & 8) ? c1 : c0;

        int rr = resolve_window<BITS>(ve, table, mapping, aux, z, zch);

#pragma unroll
        for (int j = 0; j < 16; ++j) r[j] = (e == j) ? rr : r[j];
    }

    vint4 oa, ob, oc, od;
    oa.x = r[0];  oa.y = r[1];  oa.z = r[2];  oa.w = r[3];
    ob.x = r[4];  ob.y = r[5];  ob.z = r[6];  ob.w = r[7];
    oc.x = r[8];  oc.y = r[9];  oc.z = r[10]; oc.w = r[11];
    od.x = r[12]; od.y = r[13]; od.z = r[14]; od.w = r[15];
    __builtin_nontemporal_store(oa, out4 + i);
    __builtin_nontemporal_store(ob, out4 + i + q4);
    __builtin_nontemporal_store(oc, out4 + i + 2 * q4);
    __builtin_nontemporal_store(od, out4 + i + 3 * q4);
}

// scalar tail (n % 16 != 0)
template <int BITS>
__global__ __launch_bounds__(64) void mch_remap_tail_kernel(
    const int* __restrict__ values, const int* __restrict__ table,
    const int* __restrict__ mapping, const int* __restrict__ zch_p,
    const int* __restrict__ aux, const u64* __restrict__ filter,
    int* __restrict__ out, int start, int n, int z) {
    const int SH = 31 - BITS;
    int i = start + blockIdx.x * blockDim.x + threadIdx.x;
    if (i >= n) return;
    int v = values[i];
    u64 w = filter[((unsigned)v) >> SH];
    u64 mask = sig_mask((unsigned)v);
    int zch = *zch_p;
    out[i] = ((w & mask) == mask)
                 ? resolve_window<BITS>(v, table, mapping, aux, z, zch) : zch;
}

// ---- fallback: aux-only windowed count, ~2 MB ws ----
__global__ __launch_bounds__(256) void mch_remap_aux_kernel(
    const int* __restrict__ values, const int* __restrict__ table,
    const int* __restrict__ mapping, const int* __restrict__ zch_p,
    const int* __restrict__ aux, int* __restrict__ out, int n, int z) {
    int zch = *zch_p;
    int i = blockIdx.x * blockDim.x + threadIdx.x;
    if (i >= n) return;
    int v = __builtin_nontemporal_load(values + i);
    out[i] = resolve_window<19>(v, table, mapping, aux, z, zch);
}

template <int BITS>
static void run_bloom(const int* values, const int* table, const int* mapping,
                      const int* zch_p, int* out, int n, int z, int m,
                      void* d_ws, hipStream_t stream) {
    const unsigned NB = 1u << BITS;
    u64* filter = (u64*)d_ws;
    int* aux = (int*)((char*)d_ws + (size_t)NB * 8);
    const int block = 256;

    build_aux_scatter<BITS><<<(m + block - 1) / block, block, 0, stream>>>(
        table, m, aux);
    build_sigs<BITS><<<((int)NB + block - 1) / block, block, 0, stream>>>(
        table, aux, z, filter);

    int q4 = n >> 4;                     // int4 units per segment (16 vals/thread)
    if (q4 > 0) {
        mch_remap_bloom_kernel<BITS><<<(q4 + block - 1) / block, block, 0, stream>>>(
            (const vint4*)values, table, mapping, zch_p, aux, filter,
            (vint4*)out, q4, z);
    }
    int done = (q4 << 4);
    if (done < n) {
        mch_remap_tail_kernel<BITS><<<((n - done) + 63) / 64, 64, 0, stream>>>(
            values, table, mapping, zch_p, aux, filter, out, done, n, z);
    }
}

extern "C" void kernel_launch(void* const* d_in, const int* in_sizes, int n_in,
                              void* d_out, int out_size, void* d_ws, size_t ws_size,
                              hipStream_t stream) {
    const int* values  = (const int*)d_in[0];
    const int* table   = (const int*)d_in[1];
    const int* mapping = (const int*)d_in[2];
    const int* zch_p   = (const int*)d_in[3];
    int* out = (int*)d_out;

    int n = in_sizes[0];          // 33_554_432
    int z = in_sizes[1];          // 4_194_304
    int m = z - 1;

    const size_t need19 = (size_t)(1u << 19) * 8 + ((size_t)(1u << 19) + 1) * 4;
    const size_t aux19  = ((size_t)(1u << 19) + 1) * 4;
    const int block = 256;

    if (ws_size >= need19) {
        run_bloom<19>(values, table, mapping, zch_p, out, n, z, m, d_ws, stream);
    } else if (ws_size >= aux19) {
        int* aux = (int*)d_ws;
        build_aux_scatter<19><<<(m + block - 1) / block, block, 0, stream>>>(
            table, m, aux);
        mch_remap_aux_kernel<<<(n + block - 1) / block, block, 0, stream>>>(
            values, table, mapping, zch_p, aux, out, n, z);
    }
}